// Round 5
// baseline (197.628 us; speedup 1.0000x reference)
//
#include <hip/hip_runtime.h>

#define LAMBDA_COORD 5.0f
#define LAMBDA_NOOBJ 0.5f
#define NBLK 1024      // persistent blocks (4 per CU)
#define CHUNK 128      // cells per chunk

// 802816 cells; preds 30 f32/cell (120 B), targets 25 f32/cell (100 B).
//
// v6: v1-v5 proved 66-70 us is invariant to access pattern, mechanism
// (VMEM/DMA), occupancy (13-60%), fetched bytes, and reduction tail
// (atomic vs store). All were ONE-SHOT blocks: burst 14 loads -> stall ->
// retire. The 6.3 TB/s copy ubench is a PERSISTENT grid-stride loop with
// steady-state request pressure. v6 replicates that: 1024 persistent
// blocks, each software-pipelined over 128-cell chunks (prefetch chunk
// k+1 into regs while computing chunk k from LDS). If this also lands at
// ~66 us, the 2.6-2.7 TB/s composite service rate is the machine's wall
// for this footprint -> roofline.

typedef float f4 __attribute__((ext_vector_type(4)));           // 16-aligned
typedef float f4u __attribute__((ext_vector_type(4), aligned(4)));
typedef float f2u __attribute__((ext_vector_type(2), aligned(4)));

__global__ void zero_out_kernel(float* out, int n) {
    int i = blockIdx.x * blockDim.x + threadIdx.x;
    if (i < n) out[i] = 0.0f;
}

// per-cell loss from LDS-resident cell (strict reference op order)
__device__ __forceinline__ float cell_loss(const float* __restrict__ P,
                                           const float* __restrict__ T) {
    float q0 = P[0], q1 = P[1], q2 = P[2], q3 = P[3], q4 = P[4];
    float q5 = P[5], q6 = P[6], q7 = P[7], q8 = P[8], q9 = P[9];

    // jnp.argmax picks first index on tie -> box1 only on strict greater.
    bool pick1 = q5 > q0;
    float b0 = pick1 ? q5 : q0;
    float b1 = pick1 ? q6 : q1;
    float b2 = pick1 ? q7 : q2;
    float b3 = pick1 ? q8 : q3;
    float b4 = pick1 ? q9 : q4;

    float t0 = T[0];
    float d1 = b1 - T[1], d2 = b2 - T[2], d3 = b3 - T[3], d4 = b4 - T[4];
    float box_loss = d1 * d1 + d2 * d2 + d3 * d3 + d4 * d4;
    float dpc = b0 - t0;
    float pc_loss = dpc * dpc;

    float cl = 0.0f;
    #pragma unroll
    for (int k = 0; k < 20; ++k) {
        float d = P[10 + k] - T[5 + k];
        cl += d * d;
    }

    float obj_term = LAMBDA_COORD * box_loss + pc_loss + cl;
    float noobj_term = LAMBDA_NOOBJ * (q0 * q0 + q5 * q5);
    return (t0 == 1.0f) ? obj_term : noobj_term;
}

__global__ __launch_bounds__(256, 4) void yolo_loss_kernel(
    const float* __restrict__ preds, const float* __restrict__ targets,
    float* __restrict__ ws, int nchunk)
{
    __shared__ float sp[CHUNK * 30];   // 15360 B
    __shared__ float st[CHUNK * 25];   // 12800 B
    __shared__ float s_part[4];

    const int tid = threadIdx.x;
    const int stride = gridDim.x;
    f4* sp4 = (f4*)sp;
    f4* st4 = (f4*)st;

    float acc = 0.0f;
    int g = blockIdx.x;

    if (g < nchunk) {
        // prologue: prefetch first chunk into registers (wave-linear f4)
        f4 a0, a1, a2, a3, b0, b1, b2, b3;
        {
            const f4* pg = (const f4*)(preds + (size_t)g * (CHUNK * 30));
            const f4* tg = (const f4*)(targets + (size_t)g * (CHUNK * 25));
            a0 = pg[tid]; a1 = pg[tid + 256]; a2 = pg[tid + 512];
            if (tid < 192) a3 = pg[tid + 768];           // 960 f4 total
            b0 = tg[tid]; b1 = tg[tid + 256]; b2 = tg[tid + 512];
            if (tid < 32) b3 = tg[tid + 768];            // 800 f4 total
        }

        for (;;) {
            // stage current chunk regs -> LDS (linear ds_write_b128)
            sp4[tid] = a0; sp4[tid + 256] = a1; sp4[tid + 512] = a2;
            if (tid < 192) sp4[tid + 768] = a3;
            st4[tid] = b0; st4[tid + 256] = b1; st4[tid + 512] = b2;
            if (tid < 32) st4[tid + 768] = b3;
            __syncthreads();

            const int gn = g + stride;
            const bool more = gn < nchunk;
            if (more) {
                // issue next chunk's loads NOW -- they fly under the compute
                const f4* pg = (const f4*)(preds + (size_t)gn * (CHUNK * 30));
                const f4* tg = (const f4*)(targets + (size_t)gn * (CHUNK * 25));
                a0 = pg[tid]; a1 = pg[tid + 256]; a2 = pg[tid + 512];
                if (tid < 192) a3 = pg[tid + 768];
                b0 = tg[tid]; b1 = tg[tid + 256]; b2 = tg[tid + 512];
                if (tid < 32) b3 = tg[tid + 768];
            }

            if (tid < CHUNK)
                acc += cell_loss(sp + tid * 30, st + tid * 25);

            if (!more) break;
            __syncthreads();   // everyone done reading LDS before overwrite
            g = gn;
        }
    }

    // block reduction (wave shuffle + LDS partials), deterministic store
    #pragma unroll
    for (int off = 32; off > 0; off >>= 1)
        acc += __shfl_down(acc, off, 64);
    if ((tid & 63) == 0) s_part[tid >> 6] = acc;
    __syncthreads();
    if (tid == 0)
        ws[blockIdx.x] = s_part[0] + s_part[1] + s_part[2] + s_part[3];
}

__global__ __launch_bounds__(256) void reduce_ws_kernel(
    const float* __restrict__ ws,
    const float* __restrict__ preds, const float* __restrict__ targets,
    float* __restrict__ out, int nblk, int tail_start, int n_cells)
{
    __shared__ float s_part[4];
    const int tid = threadIdx.x;

    float s = 0.0f;
    for (int i = tid; i < nblk; i += 256) s += ws[i];

    // generic tail (n_cells % CHUNK != 0) -- unused at this problem size
    const int c = tail_start + tid;
    if (c < n_cells) {
        const float* pbase = preds + (size_t)c * 30;
        const float* tbase = targets + (size_t)c * 25;
        const f4u* pp = (const f4u*)pbase;
        const f4u* tp = (const f4u*)tbase;

        f4u P0 = pp[0], P1 = pp[1], P2 = pp[2], P3 = pp[3];
        f4u P4 = pp[4], P5 = pp[5], P6 = pp[6];
        f2u P7 = *(const f2u*)(pbase + 28);
        f4u T0 = tp[0], T1 = tp[1], T2 = tp[2], T3 = tp[3];
        f4u T4 = tp[4], T5 = tp[5];
        float t24 = tbase[24];

        float p0 = P0.x, p5c = P1.y;
        bool pick1 = p5c > p0;
        float b0 = pick1 ? p5c  : p0;
        float b1 = pick1 ? P1.z : P0.y;
        float b2 = pick1 ? P1.w : P0.z;
        float b3 = pick1 ? P2.x : P0.w;
        float b4 = pick1 ? P2.y : P1.x;

        float t0 = T0.x;
        float d1 = b1 - T0.y, d2 = b2 - T0.z, d3 = b3 - T0.w, d4 = b4 - T1.x;
        float box_loss = d1 * d1 + d2 * d2 + d3 * d3 + d4 * d4;
        float dpc = b0 - t0;
        float pc_loss = dpc * dpc;

        float cl = 0.0f, d;
        d = P2.z - T1.y; cl += d * d;
        d = P2.w - T1.z; cl += d * d;
        d = P3.x - T1.w; cl += d * d;
        d = P3.y - T2.x; cl += d * d;
        d = P3.z - T2.y; cl += d * d;
        d = P3.w - T2.z; cl += d * d;
        d = P4.x - T2.w; cl += d * d;
        d = P4.y - T3.x; cl += d * d;
        d = P4.z - T3.y; cl += d * d;
        d = P4.w - T3.z; cl += d * d;
        d = P5.x - T3.w; cl += d * d;
        d = P5.y - T4.x; cl += d * d;
        d = P5.z - T4.y; cl += d * d;
        d = P5.w - T4.z; cl += d * d;
        d = P6.x - T4.w; cl += d * d;
        d = P6.y - T5.x; cl += d * d;
        d = P6.z - T5.y; cl += d * d;
        d = P6.w - T5.z; cl += d * d;
        d = P7.x - T5.w; cl += d * d;
        d = P7.y - t24;  cl += d * d;

        float obj_term = LAMBDA_COORD * box_loss + pc_loss + cl;
        float noobj_term = LAMBDA_NOOBJ * (p0 * p0 + p5c * p5c);
        s += (t0 == 1.0f) ? obj_term : noobj_term;
    }

    #pragma unroll
    for (int off = 32; off > 0; off >>= 1)
        s += __shfl_down(s, off, 64);
    if ((tid & 63) == 0) s_part[tid >> 6] = s;
    __syncthreads();
    if (tid == 0)
        out[0] = s_part[0] + s_part[1] + s_part[2] + s_part[3];
}

extern "C" void kernel_launch(void* const* d_in, const int* in_sizes, int n_in,
                              void* d_out, int out_size, void* d_ws, size_t ws_size,
                              hipStream_t stream) {
    const float* preds   = (const float*)d_in[0];
    const float* targets = (const float*)d_in[1];
    float* out = (float*)d_out;
    float* ws  = (float*)d_ws;

    const int n_cells = in_sizes[0] / 30;        // 802816
    const int nchunk = n_cells / CHUNK;          // 6272
    const int tail_start = nchunk * CHUNK;       // == n_cells here

    // d_out is poisoned (0xAA) before every timed replay — zero it on-stream.
    zero_out_kernel<<<(out_size + 255) / 256, 256, 0, stream>>>(out, out_size);

    int grid = NBLK;
    if (grid > nchunk) grid = nchunk;
    yolo_loss_kernel<<<grid, 256, 0, stream>>>(preds, targets, ws, nchunk);
    reduce_ws_kernel<<<1, 256, 0, stream>>>(ws, preds, targets, out,
                                            grid, tail_start, n_cells);
}